// Round 1
// baseline (523.186 us; speedup 1.0000x reference)
//
#include <hip/hip_runtime.h>

#define ETH 256

__device__ __forceinline__ float frelu(float x) { return fmaxf(x, 0.0f); }

// ---------------- prep: transposed + scaled TP weight tables ----------------
// W1t[col*16+k] = fcW2[k*576+col] * (1/sqrt(16)) * scale1(col)
//   scale1: ss [0,288): 1/sqrt(48) ; vs [288,432): 1/sqrt(24)
//           sv [432,528): sqrt(3)/sqrt(48) ; vv [528,576): 1/sqrt(24)
// W2t[col*16+k] = fc2W2[k*144+col] * (1/sqrt(16)) * scale2(col)
//   scale2: ss [0,64): 1/4 ; vs [64,96): 1/sqrt(8)
//           sv [96,128): sqrt(3)/4 ; vv [128,144): 1/sqrt(8)
__global__ void prep_kernel(const float* __restrict__ fcW2,
                            const float* __restrict__ fc2W2,
                            float* __restrict__ W1t,
                            float* __restrict__ W2t) {
    const float SQ3 = 1.7320508075688772f;
    const float cs1 = 0.14433756729740643f;   // 1/sqrt(48)
    const float cv1 = 0.20412414523193150f;   // 1/sqrt(24)
    const float cs2 = 0.25f;                  // 1/sqrt(16)
    const float cv2 = 0.35355339059327373f;   // 1/sqrt(8)
    int idx = blockIdx.x * blockDim.x + threadIdx.x;
    if (idx < 576 * 16) {
        int col = idx >> 4, k = idx & 15;
        float s = (col < 288) ? cs1 : (col < 432) ? cv1 : (col < 528) ? SQ3 * cs1 : cv1;
        W1t[idx] = fcW2[k * 576 + col] * 0.25f * s;
    }
    if (idx < 144 * 16) {
        int col = idx >> 4, k = idx & 15;
        float s = (col < 64) ? cs2 : (col < 96) ? cv2 : (col < 128) ? SQ3 * cs2 : cv2;
        W2t[idx] = fc2W2[k * 144 + col] * 0.25f * s;
    }
}

// ---------------- edge kernel: MLPs + TP1 + gate + TP2 + scatter ----------------
__global__ __launch_bounds__(ETH) void edge_kernel(
    const float* __restrict__ hn, const float* __restrict__ he,
    const int* __restrict__ esrc, const int* __restrict__ edst,
    const float* __restrict__ evec, const float* __restrict__ emb,
    const float* __restrict__ enorm,
    const float* __restrict__ fcW1, const float* __restrict__ fc2W1,
    const float* __restrict__ W1t, const float* __restrict__ W2t,
    float* __restrict__ he_out, float* __restrict__ node_ftr, int E) {

    __shared__ float tls[ETH][21];   // per-thread: 8 tmp_s + 12 tmp_v (stride 21: no bank conflict)
    int e = blockIdx.x * blockDim.x + threadIdx.x;
    if (e >= E) return;
    float* my = tls[threadIdx.x];

    // ---- MLP hidden layers (both MLPs share scaled emb) ----
    float em[10];
#pragma unroll
    for (int i = 0; i < 10; ++i) em[i] = emb[(size_t)e * 10 + i] * 0.31622776601683794f; // /sqrt(10)

    float h[16], h2[16];
#pragma unroll
    for (int j = 0; j < 16; ++j) {
        float a = 0.f, b = 0.f;
#pragma unroll
        for (int i = 0; i < 10; ++i) {
            a = fmaf(em[i], fcW1[i * 16 + j], a);
            b = fmaf(em[i], fc2W1[i * 16 + j], b);
        }
        h[j] = frelu(a);
        h2[j] = frelu(b);
    }

    // ---- unit edge vector ----
    float vx = evec[(size_t)e * 3 + 0], vy = evec[(size_t)e * 3 + 1], vz = evec[(size_t)e * 3 + 2];
    float inv = 1.0f / (sqrtf(fmaf(vx, vx, fmaf(vy, vy, vz * vz))) + 1e-12f);
    float u0 = vx * inv, u1 = vy * inv, u2 = vz * inv;

    const float* he_row = he + (size_t)e * 20;
    int ns = esrc[e], nd = edst[e];
    const float* hs_row = hn + (size_t)ns * 20;
    const float* hd_row = hn + (size_t)nd * 20;

    // ---- TP1 ----
    float out0[12], qsv[4], o1x[4], o1y[4], o1z[4];
#pragma unroll
    for (int o = 0; o < 12; ++o) out0[o] = 0.f;
#pragma unroll
    for (int o = 0; o < 4; ++o) { qsv[o] = 0.f; o1x[o] = 0.f; o1y[o] = 0.f; o1z[o] = 0.f; }

    // scalar part: i in [0,24) over {he_s, hn_s[src], hn_s[dst]}
#pragma unroll
    for (int blk = 0; blk < 3; ++blk) {
        const float* sp = (blk == 0) ? he_row : (blk == 1) ? hs_row : hd_row;
#pragma unroll 2
        for (int ii = 0; ii < 8; ++ii) {
            float si = sp[ii];
            int i = blk * 8 + ii;
            const float* wss = W1t + (size_t)(i * 12) * 16;
            const float* wsv = W1t + (size_t)(432 + i * 4) * 16;
#pragma unroll
            for (int o = 0; o < 12; ++o) {
                float w = 0.f;
#pragma unroll
                for (int k = 0; k < 16; ++k) w = fmaf(h[k], wss[o * 16 + k], w);
                out0[o] = fmaf(si, w, out0[o]);
            }
#pragma unroll
            for (int o = 0; o < 4; ++o) {
                float w = 0.f;
#pragma unroll
                for (int k = 0; k < 16; ++k) w = fmaf(h[k], wsv[o * 16 + k], w);
                qsv[o] = fmaf(si, w, qsv[o]);
            }
        }
    }

    // vector part: i in [0,12) over {he_v, hn_v[src], hn_v[dst]}
#pragma unroll
    for (int blk = 0; blk < 3; ++blk) {
        const float* vp = ((blk == 0) ? he_row : (blk == 1) ? hs_row : hd_row) + 8;
#pragma unroll 2
        for (int ii = 0; ii < 4; ++ii) {
            float wx = vp[ii * 3 + 0], wy = vp[ii * 3 + 1], wz = vp[ii * 3 + 2];
            float dot = fmaf(wx, u0, fmaf(wy, u1, wz * u2));
            int i = blk * 4 + ii;
            const float* wvs = W1t + (size_t)(288 + i * 12) * 16;
            const float* wvv = W1t + (size_t)(528 + i * 4) * 16;
#pragma unroll
            for (int o = 0; o < 12; ++o) {
                float w = 0.f;
#pragma unroll
                for (int k = 0; k < 16; ++k) w = fmaf(h[k], wvs[o * 16 + k], w);
                out0[o] = fmaf(dot, w, out0[o]);
            }
#pragma unroll
            for (int o = 0; o < 4; ++o) {
                float w = 0.f;
#pragma unroll
                for (int k = 0; k < 16; ++k) w = fmaf(h[k], wvv[o * 16 + k], w);
                o1x[o] = fmaf(wx, w, o1x[o]);
                o1y[o] = fmaf(wy, w, o1y[o]);
                o1z[o] = fmaf(wz, w, o1z[o]);
            }
        }
    }
#pragma unroll
    for (int o = 0; o < 4; ++o) {   // sv term: u_c * sum_i s_i w_sv  (sqrt3*c_s folded)
        o1x[o] = fmaf(qsv[o], u0, o1x[o]);
        o1y[o] = fmaf(qsv[o], u1, o1y[o]);
        o1z[o] = fmaf(qsv[o], u2, o1z[o]);
    }

    // ---- gating -> LDS scratch ----
#pragma unroll
    for (int o = 0; o < 8; ++o) my[o] = frelu(out0[o]);
#pragma unroll
    for (int o = 0; o < 4; ++o) {
        float g = frelu(out0[8 + o]);
        my[8 + o * 3 + 0] = o1x[o] * g;
        my[8 + o * 3 + 1] = o1y[o] * g;
        my[8 + o * 3 + 2] = o1z[o] * g;
    }

    // ---- TP2 ----
    float d0[8], q2[4], d1x[4], d1y[4], d1z[4];
#pragma unroll
    for (int o = 0; o < 8; ++o) d0[o] = 0.f;
#pragma unroll
    for (int o = 0; o < 4; ++o) { q2[o] = 0.f; d1x[o] = 0.f; d1y[o] = 0.f; d1z[o] = 0.f; }

#pragma unroll 2
    for (int i = 0; i < 8; ++i) {   // scalar part
        float si = my[i];
        const float* wss = W2t + (size_t)(i * 8) * 16;
        const float* wsv = W2t + (size_t)(96 + i * 4) * 16;
#pragma unroll
        for (int o = 0; o < 8; ++o) {
            float w = 0.f;
#pragma unroll
            for (int k = 0; k < 16; ++k) w = fmaf(h2[k], wss[o * 16 + k], w);
            d0[o] = fmaf(si, w, d0[o]);
        }
#pragma unroll
        for (int o = 0; o < 4; ++o) {
            float w = 0.f;
#pragma unroll
            for (int k = 0; k < 16; ++k) w = fmaf(h2[k], wsv[o * 16 + k], w);
            q2[o] = fmaf(si, w, q2[o]);
        }
    }
#pragma unroll 2
    for (int i = 0; i < 4; ++i) {   // vector part
        float wx = my[8 + i * 3 + 0], wy = my[8 + i * 3 + 1], wz = my[8 + i * 3 + 2];
        float dot = fmaf(wx, u0, fmaf(wy, u1, wz * u2));
        const float* wvs = W2t + (size_t)(64 + i * 8) * 16;
        const float* wvv = W2t + (size_t)(128 + i * 4) * 16;
#pragma unroll
        for (int o = 0; o < 8; ++o) {
            float w = 0.f;
#pragma unroll
            for (int k = 0; k < 16; ++k) w = fmaf(h2[k], wvs[o * 16 + k], w);
            d0[o] = fmaf(dot, w, d0[o]);
        }
#pragma unroll
        for (int o = 0; o < 4; ++o) {
            float w = 0.f;
#pragma unroll
            for (int k = 0; k < 16; ++k) w = fmaf(h2[k], wvv[o * 16 + k], w);
            d1x[o] = fmaf(wx, w, d1x[o]);
            d1y[o] = fmaf(wy, w, d1y[o]);
            d1z[o] = fmaf(wz, w, d1z[o]);
        }
    }
#pragma unroll
    for (int o = 0; o < 4; ++o) {
        d1x[o] = fmaf(q2[o], u0, d1x[o]);
        d1y[o] = fmaf(q2[o], u1, d1y[o]);
        d1z[o] = fmaf(q2[o], u2, d1z[o]);
    }

    // ---- he_new, write + scatter ----
    float hnew[20];
#pragma unroll
    for (int j = 0; j < 8; ++j) hnew[j] = he_row[j] + d0[j];
#pragma unroll
    for (int o = 0; o < 4; ++o) {
        hnew[8 + o * 3 + 0] = he_row[8 + o * 3 + 0] + d1x[o];
        hnew[8 + o * 3 + 1] = he_row[8 + o * 3 + 1] + d1y[o];
        hnew[8 + o * 3 + 2] = he_row[8 + o * 3 + 2] + d1z[o];
    }
    float* hep = he_out + (size_t)e * 20;
#pragma unroll
    for (int j = 0; j < 20; ++j) hep[j] = hnew[j];

    float nw = enorm[e];
    float* nf = node_ftr + (size_t)nd * 20;
#pragma unroll
    for (int j = 0; j < 20; ++j) atomicAdd(&nf[j], hnew[j] * nw);
}

// ---------------- node kernel ----------------
__global__ __launch_bounds__(256) void node_kernel(
    const float* __restrict__ hn, const float* __restrict__ node_ftr,
    const float* __restrict__ WgS, const float* __restrict__ WgV,
    const float* __restrict__ WoS, const float* __restrict__ WoV,
    float* __restrict__ out, int N) {
    int n = blockIdx.x * blockDim.x + threadIdx.x;
    if (n >= N) return;
    const float* hr = hn + (size_t)n * 20;
    const float* fr = node_ftr + (size_t)n * 20;
    const float rs16 = 0.25f, rs8 = 0.35355339059327373f, rs4 = 0.5f;

    float cs[16], cvx[8], cvy[8], cvz[8];
#pragma unroll
    for (int i = 0; i < 8; ++i) { cs[i] = hr[i]; cs[8 + i] = fr[i]; }
#pragma unroll
    for (int i = 0; i < 4; ++i) {
        cvx[i] = hr[8 + i * 3]; cvy[i] = hr[8 + i * 3 + 1]; cvz[i] = hr[8 + i * 3 + 2];
        cvx[4 + i] = fr[8 + i * 3]; cvy[4 + i] = fr[8 + i * 3 + 1]; cvz[4 + i] = fr[8 + i * 3 + 2];
    }
    float gl[12];
#pragma unroll
    for (int o = 0; o < 12; ++o) {
        float a = 0.f;
#pragma unroll
        for (int i = 0; i < 16; ++i) a = fmaf(cs[i], WgS[i * 12 + o], a);
        gl[o] = a * rs16;
    }
    float vlx[4], vly[4], vlz[4];
#pragma unroll
    for (int o = 0; o < 4; ++o) {
        float ax = 0.f, ay = 0.f, az = 0.f;
#pragma unroll
        for (int i = 0; i < 8; ++i) {
            float w = WgV[i * 4 + o];
            ax = fmaf(cvx[i], w, ax); ay = fmaf(cvy[i], w, ay); az = fmaf(cvz[i], w, az);
        }
        float g = frelu(gl[8 + o]);
        vlx[o] = ax * rs8 * g; vly[o] = ay * rs8 * g; vlz[o] = az * rs8 * g;
    }
    float ls[8];
#pragma unroll
    for (int i = 0; i < 8; ++i) ls[i] = frelu(gl[i]);
    float* op = out + (size_t)n * 20;
#pragma unroll
    for (int o = 0; o < 8; ++o) {
        float a = 0.f;
#pragma unroll
        for (int i = 0; i < 8; ++i) a = fmaf(ls[i], WoS[i * 8 + o], a);
        op[o] = hr[o] + a * rs8;
    }
#pragma unroll
    for (int o = 0; o < 4; ++o) {
        float ax = 0.f, ay = 0.f, az = 0.f;
#pragma unroll
        for (int i = 0; i < 4; ++i) {
            float w = WoV[i * 4 + o];
            ax = fmaf(vlx[i], w, ax); ay = fmaf(vly[i], w, ay); az = fmaf(vlz[i], w, az);
        }
        op[8 + o * 3 + 0] = hr[8 + o * 3 + 0] + ax * rs4;
        op[8 + o * 3 + 1] = hr[8 + o * 3 + 1] + ay * rs4;
        op[8 + o * 3 + 2] = hr[8 + o * 3 + 2] + az * rs4;
    }
}

extern "C" void kernel_launch(void* const* d_in, const int* in_sizes, int n_in,
                              void* d_out, int out_size, void* d_ws, size_t ws_size,
                              hipStream_t stream) {
    const float* hn    = (const float*)d_in[0];
    const float* he    = (const float*)d_in[1];
    const int*   esrc  = (const int*)d_in[2];
    const int*   edst  = (const int*)d_in[3];
    const float* evec  = (const float*)d_in[4];
    const float* emb   = (const float*)d_in[5];
    const float* enorm = (const float*)d_in[6];
    const float* fcW1  = (const float*)d_in[8];
    const float* fcW2  = (const float*)d_in[9];
    const float* fc2W1 = (const float*)d_in[10];
    const float* fc2W2 = (const float*)d_in[11];
    const float* WgS   = (const float*)d_in[12];
    const float* WgV   = (const float*)d_in[13];
    const float* WoS   = (const float*)d_in[14];
    const float* WoV   = (const float*)d_in[15];

    int N = in_sizes[0] / 20;
    int E = in_sizes[1] / 20;

    float* out     = (float*)d_out;
    float* he_out  = out + (size_t)N * 20;
    float* node_ftr = (float*)d_ws;                    // N*20 floats
    float* W1t = node_ftr + (size_t)N * 20;            // 576*16 floats
    float* W2t = W1t + 576 * 16;                       // 144*16 floats

    hipMemsetAsync(node_ftr, 0, (size_t)N * 20 * sizeof(float), stream);
    prep_kernel<<<(576 * 16 + 255) / 256, 256, 0, stream>>>(fcW2, fc2W2, W1t, W2t);
    edge_kernel<<<(E + ETH - 1) / ETH, ETH, 0, stream>>>(
        hn, he, esrc, edst, evec, emb, enorm, fcW1, fc2W1, W1t, W2t, he_out, node_ftr, E);
    node_kernel<<<(N + 255) / 256, 256, 0, stream>>>(hn, node_ftr, WgS, WgV, WoS, WoV, out, N);
}

// Round 3
// 357.516 us; speedup vs baseline: 1.4634x; 1.4634x over previous
//
#include <hip/hip_runtime.h>

typedef __attribute__((ext_vector_type(8))) short bf16x8;
typedef __attribute__((ext_vector_type(4))) short bf16x4;
typedef __attribute__((ext_vector_type(4))) float f32x4;
typedef unsigned short ushort_t;

#define EPB 256   // edges per block (4 waves)
#define ST  64    // edges per GEMM subtile

__device__ __forceinline__ float frelu(float x) { return fmaxf(x, 0.0f); }

// bf16 <-> f32 via bit ops (no API dependence). RNE rounding on the way down.
__device__ __forceinline__ ushort_t f2bf(float f) {
    unsigned u = __float_as_uint(f);
    u = (u + 0x7FFFu + ((u >> 16) & 1u)) >> 16;
    return (ushort_t)u;
}
__device__ __forceinline__ float bf2f(ushort_t u) {
    return __uint_as_float(((unsigned)u) << 16);
}

__device__ __forceinline__ float dot8(const float* s, bf16x8 w) {
    float a = 0.f;
#pragma unroll
    for (int b = 0; b < 8; ++b) a = fmaf(s[b], bf2f((ushort_t)w[b]), a);
    return a;
}
__device__ __forceinline__ float dot4(const float* s, bf16x4 w) {
    float a = 0.f;
#pragma unroll
    for (int b = 0; b < 4; ++b) a = fmaf(s[b], bf2f((ushort_t)w[b]), a);
    return a;
}
__device__ __forceinline__ float sel4(int j, float a, float b, float c, float d) {
    float r0 = (j & 1) ? b : a;
    float r1 = (j & 1) ? d : c;
    return (j & 2) ? r1 : r0;
}

// ---------------- prep: scaled bf16 weight tables, [col][16 k] ----------------
__global__ void prep_kernel(const float* __restrict__ fcW2,
                            const float* __restrict__ fc2W2,
                            ushort_t* __restrict__ W1t,
                            ushort_t* __restrict__ W2t) {
    const float SQ3 = 1.7320508075688772f;
    const float cs1 = 0.14433756729740643f;   // 1/sqrt(48)
    const float cv1 = 0.20412414523193150f;   // 1/sqrt(24)
    const float cs2 = 0.25f;                  // 1/sqrt(16)
    const float cv2 = 0.35355339059327373f;   // 1/sqrt(8)
    int idx = blockIdx.x * blockDim.x + threadIdx.x;
    if (idx < 576 * 16) {
        int c = idx >> 4, k = idx & 15;
        float s = (c < 288) ? cs1 : (c < 432) ? cv1 : (c < 528) ? SQ3 * cs1 : cv1;
        W1t[idx] = f2bf(fcW2[k * 576 + c] * 0.25f * s);
    }
    if (idx < 144 * 16) {
        int c = idx >> 4, k = idx & 15;
        float s = (c < 64) ? cs2 : (c < 96) ? cv2 : (c < 128) ? SQ3 * cs2 : cv2;
        W2t[idx] = f2bf(fc2W2[k * 144 + c] * 0.25f * s);
    }
}

// ---------------- edge kernel: MFMA weight-gen + TP consume + scatter ----------------
__global__ __launch_bounds__(EPB) void edge_kernel(
    const float* __restrict__ hn, const float* __restrict__ he,
    const int* __restrict__ esrc, const int* __restrict__ edst,
    const float* __restrict__ evec, const float* __restrict__ emb,
    const float* __restrict__ enorm,
    const float* __restrict__ fcW1, const float* __restrict__ fc2W1,
    const ushort_t* __restrict__ W1t, const ushort_t* __restrict__ W2t,
    float* __restrict__ he_out, float* __restrict__ node_ftr, int E) {

    __shared__ ushort_t hh[EPB][40];    // per-edge h[16] | h2[16] | pad (80B rows)
    __shared__ ushort_t W1L[ST][608];   // per-edge TP1 weights, i-major per o region
    __shared__ ushort_t W2L[ST][160];   // per-edge TP2 weights
    __shared__ ushort_t tmpL[ST][32];   // raw out0[12] | out1[4][3]

    const int tid  = threadIdx.x;
    const int wave = tid >> 6;
    const int lane = tid & 63;
    const int row  = lane & 15;
    const int g    = lane >> 4;
    const long long blk = blockIdx.x;

    // ---- load B fragments once per block: 45 tiles (36 for W1, 9 for W2) ----
    bf16x8 Bf[12];
#pragma unroll
    for (int idx = 0; idx < 12; ++idx) {
        int t = wave + idx * 4;
        bf16x8 v = {};
        if (t < 45 && g < 2) {
            const ushort_t* src = (t < 36) ? (W1t + (t * 16 + row) * 16 + g * 8)
                                           : (W2t + ((t - 36) * 16 + row) * 16 + g * 8);
            v = *reinterpret_cast<const bf16x8*>(src);
        }
        Bf[idx] = v;
    }

    // ---- P0: per-edge MLP hidden layers -> LDS (bf16) ----
    {
        long long e0 = blk * EPB + tid;
        if (e0 < (long long)E) {
            float em[10];
#pragma unroll
            for (int i = 0; i < 10; ++i) em[i] = emb[e0 * 10 + i] * 0.31622776601683794f;
#pragma unroll
            for (int jj = 0; jj < 16; ++jj) {
                float a = 0.f, b = 0.f;
#pragma unroll
                for (int i = 0; i < 10; ++i) {
                    a = fmaf(em[i], fcW1[i * 16 + jj], a);
                    b = fmaf(em[i], fc2W1[i * 16 + jj], b);
                }
                hh[tid][jj]      = f2bf(frelu(a));
                hh[tid][16 + jj] = f2bf(frelu(b));
            }
        } else {
#pragma unroll
            for (int jj = 0; jj < 32; ++jj) hh[tid][jj] = 0;
        }
    }
    __syncthreads();

    const int le = tid & 63;
    const int j  = tid >> 6;   // 4 consumer threads per edge

    for (int st = 0; st < 4; ++st) {
        long long ge = blk * EPB + st * 64 + le;
        bool on = ge < (long long)E;

        // ---- prefetch all consume data (latency hides under GEMM phase) ----
        int nd = 0;
        float ex = 0, ey = 0, ez = 0, nw = 0;
        float her[20], hsr[20], hdr[20];
        if (on) {
            int ns = esrc[ge];
            nd = edst[ge];
            ex = evec[ge * 3 + 0]; ey = evec[ge * 3 + 1]; ez = evec[ge * 3 + 2];
            nw = enorm[ge];
            const float* hp = he + ge * 20;
            const float* sp = hn + (long long)ns * 20;
            const float* dp = hn + (long long)nd * 20;
#pragma unroll
            for (int q = 0; q < 20; ++q) { her[q] = hp[q]; hsr[q] = sp[q]; hdr[q] = dp[q]; }
        } else {
#pragma unroll
            for (int q = 0; q < 20; ++q) { her[q] = 0; hsr[q] = 0; hdr[q] = 0; }
        }

        // ---- GEMM phase: materialize W1eff/W2eff for this subtile ----
        bf16x8 A1[4] = {}, A2[4] = {};
        if (g < 2) {
#pragma unroll
            for (int m = 0; m < 4; ++m) {
                A1[m] = *reinterpret_cast<const bf16x8*>(&hh[st * 64 + m * 16 + row][g * 8]);
                A2[m] = *reinterpret_cast<const bf16x8*>(&hh[st * 64 + m * 16 + row][16 + g * 8]);
            }
        }
#pragma unroll
        for (int idx = 0; idx < 12; ++idx) {
            int t = wave + idx * 4;
            if (t >= 45) continue;                 // wave-uniform skip
            bool isg1 = (t < 36);
            int c = (isg1 ? t * 16 : (t - 36) * 16) + row;
            int off;
            if (isg1) {
                if (c < 288)      { int i = c / 12,          o = c % 12;         off = o * 24 + i; }
                else if (c < 432) { int i = (c - 288) / 12,  o = (c - 288) % 12; off = 288 + o * 12 + i; }
                else if (c < 528) { int i = (c - 432) >> 2,  o = (c - 432) & 3;  off = 432 + o * 24 + i; }
                else              { int i = (c - 528) >> 2,  o = (c - 528) & 3;  off = 528 + o * 12 + i; }
            } else {
                if (c < 64)       { int i = c >> 3,          o = c & 7;          off = o * 8 + i; }
                else if (c < 96)  { int i = (c - 64) >> 3,   o = (c - 64) & 7;   off = 64 + o * 4 + i; }
                else if (c < 128) { int i = (c - 96) >> 2,   o = (c - 96) & 3;   off = 96 + o * 8 + i; }
                else              { int i = (c - 128) >> 2,  o = (c - 128) & 3;  off = 128 + o * 4 + i; }
            }
            f32x4 zero = {0.f, 0.f, 0.f, 0.f};
#pragma unroll
            for (int m = 0; m < 4; ++m) {
                f32x4 d = __builtin_amdgcn_mfma_f32_16x16x32_bf16(isg1 ? A1[m] : A2[m], Bf[idx], zero, 0, 0, 0);
                int r0 = m * 16 + g * 4;           // edge row within subtile
                if (isg1) {
#pragma unroll
                    for (int r = 0; r < 4; ++r) W1L[r0 + r][off] = f2bf(d[r]);
                } else {
#pragma unroll
                    for (int r = 0; r < 4; ++r) W2L[r0 + r][off] = f2bf(d[r]);
                }
            }
        }
        __syncthreads();

        // ---- consume 1: TP1 + gate prep (4 threads per edge, split by j) ----
        float u0 = 0, u1 = 0, u2 = 0;
        if (on) {
            float inv = 1.0f / (sqrtf(fmaf(ex, ex, fmaf(ey, ey, ez * ez))) + 1e-12f);
            u0 = ex * inv; u1 = ey * inv; u2 = ez * inv;

            float dots[12];
#pragma unroll
            for (int i = 0; i < 4; ++i) {
                dots[i]     = fmaf(her[8 + i * 3], u0, fmaf(her[9 + i * 3], u1, her[10 + i * 3] * u2));
                dots[4 + i] = fmaf(hsr[8 + i * 3], u0, fmaf(hsr[9 + i * 3], u1, hsr[10 + i * 3] * u2));
                dots[8 + i] = fmaf(hdr[8 + i * 3], u0, fmaf(hdr[9 + i * 3], u1, hdr[10 + i * 3] * u2));
            }
            const ushort_t* base = &W1L[le][0];

            // out0 cols {3j, 3j+1, 3j+2}
#pragma unroll
            for (int oo = 0; oo < 3; ++oo) {
                int o = 3 * j + oo;
                bf16x8 wa = *reinterpret_cast<const bf16x8*>(base + o * 24);
                bf16x8 wb = *reinterpret_cast<const bf16x8*>(base + o * 24 + 8);
                bf16x8 wc = *reinterpret_cast<const bf16x8*>(base + o * 24 + 16);
                float acc = dot8(her, wa) + dot8(hsr, wb) + dot8(hdr, wc);
                bf16x4 va = *reinterpret_cast<const bf16x4*>(base + 288 + o * 12);
                bf16x4 vb = *reinterpret_cast<const bf16x4*>(base + 288 + o * 12 + 4);
                bf16x4 vc = *reinterpret_cast<const bf16x4*>(base + 288 + o * 12 + 8);
                acc += dot4(dots, va) + dot4(dots + 4, vb) + dot4(dots + 8, vc);
                tmpL[le][o] = f2bf(acc);
            }
            // out1[o=j] (raw, pre-gate)
            {
                bf16x8 p0 = *reinterpret_cast<const bf16x8*>(base + 432 + j * 24);
                bf16x8 p1 = *reinterpret_cast<const bf16x8*>(base + 432 + j * 24 + 8);
                bf16x8 p2 = *reinterpret_cast<const bf16x8*>(base + 432 + j * 24 + 16);
                float q = dot8(her, p0) + dot8(hsr, p1) + dot8(hdr, p2);
                bf16x4 q0 = *reinterpret_cast<const bf16x4*>(base + 528 + j * 12);
                bf16x4 q1 = *reinterpret_cast<const bf16x4*>(base + 528 + j * 12 + 4);
                bf16x4 q2 = *reinterpret_cast<const bf16x4*>(base + 528 + j * 12 + 8);
                float vx = 0, vy = 0, vz = 0;
#pragma unroll
                for (int i = 0; i < 4; ++i) {
                    float w = bf2f((ushort_t)q0[i]);
                    vx = fmaf(her[8 + i * 3], w, vx); vy = fmaf(her[9 + i * 3], w, vy); vz = fmaf(her[10 + i * 3], w, vz);
                }
#pragma unroll
                for (int i = 0; i < 4; ++i) {
                    float w = bf2f((ushort_t)q1[i]);
                    vx = fmaf(hsr[8 + i * 3], w, vx); vy = fmaf(hsr[9 + i * 3], w, vy); vz = fmaf(hsr[10 + i * 3], w, vz);
                }
#pragma unroll
                for (int i = 0; i < 4; ++i) {
                    float w = bf2f((ushort_t)q2[i]);
                    vx = fmaf(hdr[8 + i * 3], w, vx); vy = fmaf(hdr[9 + i * 3], w, vy); vz = fmaf(hdr[10 + i * 3], w, vz);
                }
                tmpL[le][12 + 3 * j + 0] = f2bf(fmaf(q, u0, vx));
                tmpL[le][12 + 3 * j + 1] = f2bf(fmaf(q, u1, vy));
                tmpL[le][12 + 3 * j + 2] = f2bf(fmaf(q, u2, vz));
            }
        }
        __syncthreads();

        // ---- consume 2: gate + TP2 + outputs + scatter ----
        if (on) {
            bf16x8 t0 = *reinterpret_cast<const bf16x8*>(&tmpL[le][0]);
            bf16x8 t1 = *reinterpret_cast<const bf16x8*>(&tmpL[le][8]);
            bf16x8 t2 = *reinterpret_cast<const bf16x8*>(&tmpL[le][16]);
            float ts[8];
#pragma unroll
            for (int b = 0; b < 8; ++b) ts[b] = frelu(bf2f((ushort_t)t0[b]));
            float gt[4];
#pragma unroll
            for (int o = 0; o < 4; ++o) gt[o] = frelu(bf2f((ushort_t)t1[o]));
            float tv[4][3];
#pragma unroll
            for (int o = 0; o < 4; ++o) {
                int s0 = 12 + 3 * o;   // slots 12..23 across t1[4..7], t2[0..7]
#pragma unroll
                for (int c = 0; c < 3; ++c) {
                    int sl = s0 + c;
                    float raw = (sl < 16) ? bf2f((ushort_t)t1[sl - 8]) : bf2f((ushort_t)t2[sl - 16]);
                    tv[o][c] = raw * gt[o];
                }
            }
            float d2[4];
#pragma unroll
            for (int i = 0; i < 4; ++i) d2[i] = fmaf(tv[i][0], u0, fmaf(tv[i][1], u1, tv[i][2] * u2));

            const ushort_t* b2 = &W2L[le][0];
            float d0v[2];
#pragma unroll
            for (int oo = 0; oo < 2; ++oo) {
                int o = 2 * j + oo;
                bf16x8 wss = *reinterpret_cast<const bf16x8*>(b2 + o * 8);
                bf16x4 wvs = *reinterpret_cast<const bf16x4*>(b2 + 64 + o * 4);
                d0v[oo] = dot8(ts, wss) + dot4(d2, wvs);
            }
            bf16x8 wsv = *reinterpret_cast<const bf16x8*>(b2 + 96 + j * 8);
            float q2s = dot8(ts, wsv);
            bf16x4 wvv = *reinterpret_cast<const bf16x4*>(b2 + 128 + j * 4);
            float e0c = 0, e1c = 0, e2c = 0;
#pragma unroll
            for (int i = 0; i < 4; ++i) {
                float w = bf2f((ushort_t)wvv[i]);
                e0c = fmaf(tv[i][0], w, e0c); e1c = fmaf(tv[i][1], w, e1c); e2c = fmaf(tv[i][2], w, e2c);
            }
            float d1x = fmaf(q2s, u0, e0c), d1y = fmaf(q2s, u1, e1c), d1z = fmaf(q2s, u2, e2c);

            float hA = sel4(j, her[0], her[2], her[4], her[6]);
            float hB = sel4(j, her[1], her[3], her[5], her[7]);
            float hC = sel4(j, her[8], her[11], her[14], her[17]);
            float hD = sel4(j, her[9], her[12], her[15], her[18]);
            float hE = sel4(j, her[10], her[13], her[16], her[19]);
            float oA = hA + d0v[0], oB = hB + d0v[1];
            float oC = hC + d1x, oD = hD + d1y, oE = hE + d1z;

            float* hep = he_out + ge * 20;
            hep[2 * j] = oA; hep[2 * j + 1] = oB;
            hep[8 + 3 * j] = oC; hep[8 + 3 * j + 1] = oD; hep[8 + 3 * j + 2] = oE;

            float* nf = node_ftr + (long long)nd * 20;
            atomicAdd(nf + 2 * j, oA * nw);
            atomicAdd(nf + 2 * j + 1, oB * nw);
            atomicAdd(nf + 8 + 3 * j, oC * nw);
            atomicAdd(nf + 8 + 3 * j + 1, oD * nw);
            atomicAdd(nf + 8 + 3 * j + 2, oE * nw);
        }
        __syncthreads();
    }
}

// ---------------- node kernel (unchanged, verified) ----------------
__global__ __launch_bounds__(256) void node_kernel(
    const float* __restrict__ hn, const float* __restrict__ node_ftr,
    const float* __restrict__ WgS, const float* __restrict__ WgV,
    const float* __restrict__ WoS, const float* __restrict__ WoV,
    float* __restrict__ out, int N) {
    int n = blockIdx.x * blockDim.x + threadIdx.x;
    if (n >= N) return;
    const float* hr = hn + (size_t)n * 20;
    const float* fr = node_ftr + (size_t)n * 20;
    const float rs16 = 0.25f, rs8 = 0.35355339059327373f, rs4 = 0.5f;

    float cs[16], cvx[8], cvy[8], cvz[8];
#pragma unroll
    for (int i = 0; i < 8; ++i) { cs[i] = hr[i]; cs[8 + i] = fr[i]; }
#pragma unroll
    for (int i = 0; i < 4; ++i) {
        cvx[i] = hr[8 + i * 3]; cvy[i] = hr[8 + i * 3 + 1]; cvz[i] = hr[8 + i * 3 + 2];
        cvx[4 + i] = fr[8 + i * 3]; cvy[4 + i] = fr[8 + i * 3 + 1]; cvz[4 + i] = fr[8 + i * 3 + 2];
    }
    float gl[12];
#pragma unroll
    for (int o = 0; o < 12; ++o) {
        float a = 0.f;
#pragma unroll
        for (int i = 0; i < 16; ++i) a = fmaf(cs[i], WgS[i * 12 + o], a);
        gl[o] = a * rs16;
    }
    float vlx[4], vly[4], vlz[4];
#pragma unroll
    for (int o = 0; o < 4; ++o) {
        float ax = 0.f, ay = 0.f, az = 0.f;
#pragma unroll
        for (int i = 0; i < 8; ++i) {
            float w = WgV[i * 4 + o];
            ax = fmaf(cvx[i], w, ax); ay = fmaf(cvy[i], w, ay); az = fmaf(cvz[i], w, az);
        }
        float gv = frelu(gl[8 + o]);
        vlx[o] = ax * rs8 * gv; vly[o] = ay * rs8 * gv; vlz[o] = az * rs8 * gv;
    }
    float ls[8];
#pragma unroll
    for (int i = 0; i < 8; ++i) ls[i] = frelu(gl[i]);
    float* op = out + (size_t)n * 20;
#pragma unroll
    for (int o = 0; o < 8; ++o) {
        float a = 0.f;
#pragma unroll
        for (int i = 0; i < 8; ++i) a = fmaf(ls[i], WoS[i * 8 + o], a);
        op[o] = hr[o] + a * rs8;
    }
#pragma unroll
    for (int o = 0; o < 4; ++o) {
        float ax = 0.f, ay = 0.f, az = 0.f;
#pragma unroll
        for (int i = 0; i < 4; ++i) {
            float w = WoV[i * 4 + o];
            ax = fmaf(vlx[i], w, ax); ay = fmaf(vly[i], w, ay); az = fmaf(vlz[i], w, az);
        }
        op[8 + o * 3 + 0] = hr[8 + o * 3 + 0] + ax * rs4;
        op[8 + o * 3 + 1] = hr[8 + o * 3 + 1] + ay * rs4;
        op[8 + o * 3 + 2] = hr[8 + o * 3 + 2] + az * rs4;
    }
}

extern "C" void kernel_launch(void* const* d_in, const int* in_sizes, int n_in,
                              void* d_out, int out_size, void* d_ws, size_t ws_size,
                              hipStream_t stream) {
    const float* hn    = (const float*)d_in[0];
    const float* he    = (const float*)d_in[1];
    const int*   esrc  = (const int*)d_in[2];
    const int*   edst  = (const int*)d_in[3];
    const float* evec  = (const float*)d_in[4];
    const float* emb   = (const float*)d_in[5];
    const float* enorm = (const float*)d_in[6];
    const float* fcW1  = (const float*)d_in[8];
    const float* fcW2  = (const float*)d_in[9];
    const float* fc2W1 = (const float*)d_in[10];
    const float* fc2W2 = (const float*)d_in[11];
    const float* WgS   = (const float*)d_in[12];
    const float* WgV   = (const float*)d_in[13];
    const float* WoS   = (const float*)d_in[14];
    const float* WoV   = (const float*)d_in[15];

    int N = in_sizes[0] / 20;
    int E = in_sizes[1] / 20;

    float* out      = (float*)d_out;
    float* he_out   = out + (size_t)N * 20;
    float* node_ftr = (float*)d_ws;                         // N*20 f32
    ushort_t* W1t   = (ushort_t*)(node_ftr + (size_t)N * 20); // 576*16 bf16
    ushort_t* W2t   = W1t + 576 * 16;                       // 144*16 bf16

    hipMemsetAsync(node_ftr, 0, (size_t)N * 20 * sizeof(float), stream);
    prep_kernel<<<(576 * 16 + 255) / 256, 256, 0, stream>>>(fcW2, fc2W2, W1t, W2t);
    edge_kernel<<<(E + EPB - 1) / EPB, EPB, 0, stream>>>(
        hn, he, esrc, edst, evec, emb, enorm, fcW1, fc2W1, W1t, W2t, he_out, node_ftr, E);
    node_kernel<<<(N + 255) / 256, 256, 0, stream>>>(hn, node_ftr, WgS, WgV, WoS, WoV, out, N);
}

// Round 9
// 256.169 us; speedup vs baseline: 2.0424x; 1.3956x over previous
//
#include <hip/hip_runtime.h>

typedef __attribute__((ext_vector_type(8))) short bf16x8;
typedef __attribute__((ext_vector_type(4))) short bf16x4;
typedef __attribute__((ext_vector_type(4))) float f32x4;
typedef unsigned short ushort_t;

#define EPB 256      // edges per block (4 waves)
#define ST  32       // edges per GEMM subtile (8 subtiles/block)
#define W1S 632      // W1L row stride (ushorts): 316 words ≡ 28 mod 32 -> b128 windows tile banks
#define W2S 168      // W2L row stride: 336 B, 16B-aligned rows
#define HHS 40       // hh row stride (80 B, 16B-aligned)
#define TPS 40       // tmpL row stride (80 B, 16B-aligned)

__device__ __forceinline__ float frelu(float x) { return fmaxf(x, 0.0f); }

__device__ __forceinline__ ushort_t f2bf(float f) {
    unsigned u = __float_as_uint(f);
    u = (u + 0x7FFFu + ((u >> 16) & 1u)) >> 16;
    return (ushort_t)u;
}
__device__ __forceinline__ float bf2f(ushort_t u) {
    return __uint_as_float(((unsigned)u) << 16);
}

__device__ __forceinline__ float dot8(const float* s, bf16x8 w) {
    float a = 0.f;
#pragma unroll
    for (int b = 0; b < 8; ++b) a = fmaf(s[b], bf2f((ushort_t)w[b]), a);
    return a;
}
__device__ __forceinline__ float dot4(const float* s, bf16x4 w) {
    float a = 0.f;
#pragma unroll
    for (int b = 0; b < 4; ++b) a = fmaf(s[b], bf2f((ushort_t)w[b]), a);
    return a;
}

// ---------------- prep: scaled bf16 weight tables, [col][16 k] ----------------
__global__ void prep_kernel(const float* __restrict__ fcW2,
                            const float* __restrict__ fc2W2,
                            ushort_t* __restrict__ W1t,
                            ushort_t* __restrict__ W2t) {
    const float SQ3 = 1.7320508075688772f;
    const float cs1 = 0.14433756729740643f;   // 1/sqrt(48)
    const float cv1 = 0.20412414523193150f;   // 1/sqrt(24)
    const float cs2 = 0.25f;                  // 1/sqrt(16)
    const float cv2 = 0.35355339059327373f;   // 1/sqrt(8)
    int idx = blockIdx.x * blockDim.x + threadIdx.x;
    if (idx < 576 * 16) {
        int c = idx >> 4, k = idx & 15;
        float s = (c < 288) ? cs1 : (c < 432) ? cv1 : (c < 528) ? SQ3 * cs1 : cv1;
        W1t[idx] = f2bf(fcW2[k * 576 + c] * 0.25f * s);
    }
    if (idx < 144 * 16) {
        int c = idx >> 4, k = idx & 15;
        float s = (c < 64) ? cs2 : (c < 96) ? cv2 : (c < 128) ? SQ3 * cs2 : cv2;
        W2t[idx] = f2bf(fc2W2[k * 144 + c] * 0.25f * s);
    }
}

// ---------------- edge kernel ----------------
__global__ __launch_bounds__(EPB) void edge_kernel(
    const float* __restrict__ hn, const float* __restrict__ he,
    const int* __restrict__ esrc, const int* __restrict__ edst,
    const float* __restrict__ evec, const float* __restrict__ emb,
    const float* __restrict__ enorm,
    const float* __restrict__ fcW1, const float* __restrict__ fc2W1,
    const ushort_t* __restrict__ W1t, const ushort_t* __restrict__ W2t,
    float* __restrict__ he_out, float* __restrict__ node_ftr, int E) {

    __shared__ ushort_t hh[EPB][HHS];   // per-edge h[16] | h2[16]
    __shared__ ushort_t W1L[ST][W1S];   // per-edge TP1 weights, i-major per o region
    __shared__ ushort_t W2L[ST][W2S];   // per-edge TP2 weights
    __shared__ ushort_t tmpL[ST][TPS];  // raw out0[12] | out1[4][3]

    const int tid  = threadIdx.x;
    const int wave = tid >> 6;
    const int lane = tid & 63;
    const int row  = lane & 15;
    const int g    = lane >> 4;
    const long long blk = blockIdx.x;

    // ---- B fragments once per block: 45 tiles (36 W1, 9 W2), 12 per wave ----
    bf16x8 Bf[12];
#pragma unroll
    for (int idx = 0; idx < 12; ++idx) {
        int t = wave + idx * 4;
        bf16x8 v = {};
        if (t < 45 && g < 2) {
            const ushort_t* src = (t < 36) ? (W1t + (t * 16 + row) * 16 + g * 8)
                                           : (W2t + ((t - 36) * 16 + row) * 16 + g * 8);
            v = *reinterpret_cast<const bf16x8*>(src);
        }
        Bf[idx] = v;
    }

    // ---- P0: per-edge MLP hidden layers -> LDS (bf16) ----
    {
        long long e0 = blk * EPB + tid;
        if (e0 < (long long)E) {
            float em[10];
#pragma unroll
            for (int i = 0; i < 10; ++i) em[i] = emb[e0 * 10 + i] * 0.31622776601683794f;
#pragma unroll
            for (int jj = 0; jj < 16; ++jj) {
                float a = 0.f, b = 0.f;
#pragma unroll
                for (int i = 0; i < 10; ++i) {
                    a = fmaf(em[i], fcW1[i * 16 + jj], a);
                    b = fmaf(em[i], fc2W1[i * 16 + jj], b);
                }
                hh[tid][jj]      = f2bf(frelu(a));
                hh[tid][16 + jj] = f2bf(frelu(b));
            }
        } else {
#pragma unroll
            for (int jj = 0; jj < 32; ++jj) hh[tid][jj] = 0;
        }
    }
    __syncthreads();

    const int le = tid & 31;   // edge within subtile
    const int j  = tid >> 5;   // 8 consumer threads per edge (j uniform per half-wave)

    for (int st = 0; st < 8; ++st) {
        long long ge = blk * EPB + st * ST + le;
        bool on = ge < (long long)E;

        // ---- prefetch consume data (hides under GEMM) ----
        int nd = 0;
        float ex = 0, ey = 0, ez = 0, nw = 0;
        float her[20], hsr[20], hdr[20];
        if (on) {
            int ns = esrc[ge];
            nd = edst[ge];
            ex = evec[ge * 3 + 0]; ey = evec[ge * 3 + 1]; ez = evec[ge * 3 + 2];
            nw = enorm[ge];
            const float* hp = he + ge * 20;
            const float* sp = hn + (long long)ns * 20;
            const float* dp = hn + (long long)nd * 20;
#pragma unroll
            for (int q = 0; q < 20; ++q) { her[q] = hp[q]; hsr[q] = sp[q]; hdr[q] = dp[q]; }
        } else {
#pragma unroll
            for (int q = 0; q < 20; ++q) { her[q] = 0; hsr[q] = 0; hdr[q] = 0; }
        }

        // ---- GEMM: materialize W1eff/W2eff for this 32-edge subtile ----
        bf16x8 A1[2] = {}, A2[2] = {};
        if (g < 2) {
#pragma unroll
            for (int m = 0; m < 2; ++m) {
                A1[m] = *reinterpret_cast<const bf16x8*>(&hh[st * ST + m * 16 + row][g * 8]);
                A2[m] = *reinterpret_cast<const bf16x8*>(&hh[st * ST + m * 16 + row][16 + g * 8]);
            }
        }
#pragma unroll
        for (int idx = 0; idx < 12; ++idx) {
            int t = wave + idx * 4;
            if (t >= 45) continue;                 // wave-uniform skip
            bool isg1 = (t < 36);
            int c = (isg1 ? t * 16 : (t - 36) * 16) + row;
            int off;
            if (isg1) {
                if (c < 288)      { int i = c / 12,          o = c % 12;         off = o * 24 + i; }
                else if (c < 432) { int i = (c - 288) / 12,  o = (c - 288) % 12; off = 288 + o * 12 + i; }
                else if (c < 528) { int i = (c - 432) >> 2,  o = (c - 432) & 3;  off = 432 + o * 24 + i; }
                else              { int i = (c - 528) >> 2,  o = (c - 528) & 3;  off = 528 + o * 12 + i; }
            } else {
                if (c < 64)       { int i = c >> 3,          o = c & 7;          off = o * 8 + i; }
                else if (c < 96)  { int i = (c - 64) >> 3,   o = (c - 64) & 7;   off = 64 + o * 4 + i; }
                else if (c < 128) { int i = (c - 96) >> 2,   o = (c - 96) & 3;   off = 96 + o * 8 + i; }
                else              { int i = (c - 128) >> 2,  o = (c - 128) & 3;  off = 128 + o * 4 + i; }
            }
            f32x4 zero = {0.f, 0.f, 0.f, 0.f};
#pragma unroll
            for (int m = 0; m < 2; ++m) {
                f32x4 d = __builtin_amdgcn_mfma_f32_16x16x32_bf16(isg1 ? A1[m] : A2[m], Bf[idx], zero, 0, 0, 0);
                int r0 = m * 16 + g * 4;           // edge row within subtile
                if (isg1) {
#pragma unroll
                    for (int r = 0; r < 4; ++r) W1L[r0 + r][off] = f2bf(d[r]);
                } else {
#pragma unroll
                    for (int r = 0; r < 4; ++r) W2L[r0 + r][off] = f2bf(d[r]);
                }
            }
        }
        __syncthreads();

        // ---- consume 1: TP1 + gate prep ----
        float u0 = 0, u1 = 0, u2 = 0;
        if (on) {
            float inv = 1.0f / (sqrtf(fmaf(ex, ex, fmaf(ey, ey, ez * ez))) + 1e-12f);
            u0 = ex * inv; u1 = ey * inv; u2 = ez * inv;
            const ushort_t* base = &W1L[le][0];

            if (j < 6) {            // waves 0-2: out0 cols {2j, 2j+1}
                float dots[12];
#pragma unroll
                for (int i = 0; i < 4; ++i) {
                    dots[i]     = fmaf(her[8 + i * 3], u0, fmaf(her[9 + i * 3], u1, her[10 + i * 3] * u2));
                    dots[4 + i] = fmaf(hsr[8 + i * 3], u0, fmaf(hsr[9 + i * 3], u1, hsr[10 + i * 3] * u2));
                    dots[8 + i] = fmaf(hdr[8 + i * 3], u0, fmaf(hdr[9 + i * 3], u1, hdr[10 + i * 3] * u2));
                }
#pragma unroll
                for (int oo = 0; oo < 2; ++oo) {
                    int o = 2 * j + oo;
                    bf16x8 wa = *reinterpret_cast<const bf16x8*>(base + o * 24);
                    bf16x8 wb = *reinterpret_cast<const bf16x8*>(base + o * 24 + 8);
                    bf16x8 wc = *reinterpret_cast<const bf16x8*>(base + o * 24 + 16);
                    float acc = dot8(her, wa) + dot8(hsr, wb) + dot8(hdr, wc);
                    bf16x4 va = *reinterpret_cast<const bf16x4*>(base + 288 + o * 12);
                    bf16x4 vb = *reinterpret_cast<const bf16x4*>(base + 288 + o * 12 + 4);
                    bf16x4 vc = *reinterpret_cast<const bf16x4*>(base + 288 + o * 12 + 8);
                    acc += dot4(dots, va) + dot4(dots + 4, vb) + dot4(dots + 8, vc);
                    tmpL[le][o] = f2bf(acc);
                }
            } else {                // wave 3: out1 o's {2(j-6), 2(j-6)+1} (raw, pre-gate)
#pragma unroll
                for (int oo = 0; oo < 2; ++oo) {
                    int o = 2 * (j - 6) + oo;
                    bf16x8 p0 = *reinterpret_cast<const bf16x8*>(base + 432 + o * 24);
                    bf16x8 p1 = *reinterpret_cast<const bf16x8*>(base + 432 + o * 24 + 8);
                    bf16x8 p2 = *reinterpret_cast<const bf16x8*>(base + 432 + o * 24 + 16);
                    float q = dot8(her, p0) + dot8(hsr, p1) + dot8(hdr, p2);
                    bf16x4 q0 = *reinterpret_cast<const bf16x4*>(base + 528 + o * 12);
                    bf16x4 q1 = *reinterpret_cast<const bf16x4*>(base + 528 + o * 12 + 4);
                    bf16x4 q2 = *reinterpret_cast<const bf16x4*>(base + 528 + o * 12 + 8);
                    float vx = 0, vy = 0, vz = 0;
#pragma unroll
                    for (int i = 0; i < 4; ++i) {
                        float w = bf2f((ushort_t)q0[i]);
                        vx = fmaf(her[8 + i * 3], w, vx); vy = fmaf(her[9 + i * 3], w, vy); vz = fmaf(her[10 + i * 3], w, vz);
                    }
#pragma unroll
                    for (int i = 0; i < 4; ++i) {
                        float w = bf2f((ushort_t)q1[i]);
                        vx = fmaf(hsr[8 + i * 3], w, vx); vy = fmaf(hsr[9 + i * 3], w, vy); vz = fmaf(hsr[10 + i * 3], w, vz);
                    }
#pragma unroll
                    for (int i = 0; i < 4; ++i) {
                        float w = bf2f((ushort_t)q2[i]);
                        vx = fmaf(hdr[8 + i * 3], w, vx); vy = fmaf(hdr[9 + i * 3], w, vy); vz = fmaf(hdr[10 + i * 3], w, vz);
                    }
                    tmpL[le][12 + 3 * o + 0] = f2bf(fmaf(q, u0, vx));
                    tmpL[le][12 + 3 * o + 1] = f2bf(fmaf(q, u1, vy));
                    tmpL[le][12 + 3 * o + 2] = f2bf(fmaf(q, u2, vz));
                }
            }
        }
        __syncthreads();

        // ---- consume 2: gate + TP2 + outputs + scatter ----
        if (on) {
            bf16x8 t0 = *reinterpret_cast<const bf16x8*>(&tmpL[le][0]);
            bf16x8 t1 = *reinterpret_cast<const bf16x8*>(&tmpL[le][8]);
            bf16x8 t2 = *reinterpret_cast<const bf16x8*>(&tmpL[le][16]);
            float ts[8];
#pragma unroll
            for (int b = 0; b < 8; ++b) ts[b] = frelu(bf2f((ushort_t)t0[b]));
            float gt[4];
#pragma unroll
            for (int o = 0; o < 4; ++o) gt[o] = frelu(bf2f((ushort_t)t1[o]));
            float tv[4][3];
#pragma unroll
            for (int o = 0; o < 4; ++o) {
#pragma unroll
                for (int c = 0; c < 3; ++c) {
                    int sl = 12 + 3 * o + c;
                    float raw = (sl < 16) ? bf2f((ushort_t)t1[sl - 8]) : bf2f((ushort_t)t2[sl - 16]);
                    tv[o][c] = raw * gt[o];
                }
            }
            float d2[4];
#pragma unroll
            for (int i = 0; i < 4; ++i) d2[i] = fmaf(tv[i][0], u0, fmaf(tv[i][1], u1, tv[i][2] * u2));

            const ushort_t* b2 = &W2L[le][0];
            float* hep = he_out + ge * 20;
            float* nf  = node_ftr + (long long)nd * 20;

            // scalar output col o = j (one per thread)
            {
                bf16x8 wss = *reinterpret_cast<const bf16x8*>(b2 + j * 8);
                bf16x4 wvs = *reinterpret_cast<const bf16x4*>(b2 + 64 + j * 4);
                float dval = dot8(ts, wss) + dot4(d2, wvs);
                float oS = he[ge * 20 + j] + dval;     // L1-hot reload (avoids runtime reg-index)
                hep[j] = oS;
                atomicAdd(nf + j, oS * nw);
            }
            // vector output o = j for j<4 (waves 0,1)
            if (j < 4) {
                bf16x8 wsv = *reinterpret_cast<const bf16x8*>(b2 + 96 + j * 8);
                float q2s = dot8(ts, wsv);
                bf16x4 wvv = *reinterpret_cast<const bf16x4*>(b2 + 128 + j * 4);
                float e0c = 0, e1c = 0, e2c = 0;
#pragma unroll
                for (int i = 0; i < 4; ++i) {
                    float w = bf2f((ushort_t)wvv[i]);
                    e0c = fmaf(tv[i][0], w, e0c); e1c = fmaf(tv[i][1], w, e1c); e2c = fmaf(tv[i][2], w, e2c);
                }
                float d1c[3] = { fmaf(q2s, u0, e0c), fmaf(q2s, u1, e1c), fmaf(q2s, u2, e2c) };
#pragma unroll
                for (int c = 0; c < 3; ++c) {
                    float oV = he[ge * 20 + 8 + 3 * j + c] + d1c[c];
                    hep[8 + 3 * j + c] = oV;
                    atomicAdd(nf + 8 + 3 * j + c, oV * nw);
                }
            }
        }
        __syncthreads();
    }
}

// ---------------- node kernel (unchanged, verified) ----------------
__global__ __launch_bounds__(256) void node_kernel(
    const float* __restrict__ hn, const float* __restrict__ node_ftr,
    const float* __restrict__ WgS, const float* __restrict__ WgV,
    const float* __restrict__ WoS, const float* __restrict__ WoV,
    float* __restrict__ out, int N) {
    int n = blockIdx.x * blockDim.x + threadIdx.x;
    if (n >= N) return;
    const float* hr = hn + (size_t)n * 20;
    const float* fr = node_ftr + (size_t)n * 20;
    const float rs16 = 0.25f, rs8 = 0.35355339059327373f, rs4 = 0.5f;

    float cs[16], cvx[8], cvy[8], cvz[8];
#pragma unroll
    for (int i = 0; i < 8; ++i) { cs[i] = hr[i]; cs[8 + i] = fr[i]; }
#pragma unroll
    for (int i = 0; i < 4; ++i) {
        cvx[i] = hr[8 + i * 3]; cvy[i] = hr[8 + i * 3 + 1]; cvz[i] = hr[8 + i * 3 + 2];
        cvx[4 + i] = fr[8 + i * 3]; cvy[4 + i] = fr[8 + i * 3 + 1]; cvz[4 + i] = fr[8 + i * 3 + 2];
    }
    float gl[12];
#pragma unroll
    for (int o = 0; o < 12; ++o) {
        float a = 0.f;
#pragma unroll
        for (int i = 0; i < 16; ++i) a = fmaf(cs[i], WgS[i * 12 + o], a);
        gl[o] = a * rs16;
    }
    float vlx[4], vly[4], vlz[4];
#pragma unroll
    for (int o = 0; o < 4; ++o) {
        float ax = 0.f, ay = 0.f, az = 0.f;
#pragma unroll
        for (int i = 0; i < 8; ++i) {
            float w = WgV[i * 4 + o];
            ax = fmaf(cvx[i], w, ax); ay = fmaf(cvy[i], w, ay); az = fmaf(cvz[i], w, az);
        }
        float gv = frelu(gl[8 + o]);
        vlx[o] = ax * rs8 * gv; vly[o] = ay * rs8 * gv; vlz[o] = az * rs8 * gv;
    }
    float ls[8];
#pragma unroll
    for (int i = 0; i < 8; ++i) ls[i] = frelu(gl[i]);
    float* op = out + (size_t)n * 20;
#pragma unroll
    for (int o = 0; o < 8; ++o) {
        float a = 0.f;
#pragma unroll
        for (int i = 0; i < 8; ++i) a = fmaf(ls[i], WoS[i * 8 + o], a);
        op[o] = hr[o] + a * rs8;
    }
#pragma unroll
    for (int o = 0; o < 4; ++o) {
        float ax = 0.f, ay = 0.f, az = 0.f;
#pragma unroll
        for (int i = 0; i < 4; ++i) {
            float w = WoV[i * 4 + o];
            ax = fmaf(vlx[i], w, ax); ay = fmaf(vly[i], w, ay); az = fmaf(vlz[i], w, az);
        }
        op[8 + o * 3 + 0] = hr[8 + o * 3 + 0] + ax * rs4;
        op[8 + o * 3 + 1] = hr[8 + o * 3 + 1] + ay * rs4;
        op[8 + o * 3 + 2] = hr[8 + o * 3 + 2] + az * rs4;
    }
}

extern "C" void kernel_launch(void* const* d_in, const int* in_sizes, int n_in,
                              void* d_out, int out_size, void* d_ws, size_t ws_size,
                              hipStream_t stream) {
    const float* hn    = (const float*)d_in[0];
    const float* he    = (const float*)d_in[1];
    const int*   esrc  = (const int*)d_in[2];
    const int*   edst  = (const int*)d_in[3];
    const float* evec  = (const float*)d_in[4];
    const float* emb   = (const float*)d_in[5];
    const float* enorm = (const float*)d_in[6];
    const float* fcW1  = (const float*)d_in[8];
    const float* fcW2  = (const float*)d_in[9];
    const float* fc2W1 = (const float*)d_in[10];
    const float* fc2W2 = (const float*)d_in[11];
    const float* WgS   = (const float*)d_in[12];
    const float* WgV   = (const float*)d_in[13];
    const float* WoS   = (const float*)d_in[14];
    const float* WoV   = (const float*)d_in[15];

    int N = in_sizes[0] / 20;
    int E = in_sizes[1] / 20;

    float* out      = (float*)d_out;
    float* he_out   = out + (size_t)N * 20;
    float* node_ftr = (float*)d_ws;                           // N*20 f32
    ushort_t* W1t   = (ushort_t*)(node_ftr + (size_t)N * 20); // 576*16 bf16
    ushort_t* W2t   = W1t + 576 * 16;                         // 144*16 bf16

    hipMemsetAsync(node_ftr, 0, (size_t)N * 20 * sizeof(float), stream);
    prep_kernel<<<(576 * 16 + 255) / 256, 256, 0, stream>>>(fcW2, fc2W2, W1t, W2t);
    edge_kernel<<<(E + EPB - 1) / EPB, EPB, 0, stream>>>(
        hn, he, esrc, edst, evec, emb, enorm, fcW1, fc2W1, W1t, W2t, he_out, node_ftr, E);
    node_kernel<<<(N + 255) / 256, 256, 0, stream>>>(hn, node_ftr, WgS, WgV, WoS, WoV, out, N);
}

// Round 11
// 211.446 us; speedup vs baseline: 2.4743x; 1.2115x over previous
//
#include <hip/hip_runtime.h>

typedef __attribute__((ext_vector_type(8))) short bf16x8;
typedef __attribute__((ext_vector_type(4))) short bf16x4;
typedef __attribute__((ext_vector_type(4))) float f32x4;
typedef unsigned short ushort_t;

#define EPB 256      // edges per block (4 waves)
#define ST  16       // edges per GEMM subtile (16 subtiles/block)
#define W1S 632      // W1L row stride (ushorts): 316 words ≡ 28 mod 32
#define W2S 168      // W2L row stride
#define HHS 40       // hh row stride (80 B, 16B-aligned)
#define TPS 40       // tmpL row stride

__device__ __forceinline__ float frelu(float x) { return fmaxf(x, 0.0f); }

__device__ __forceinline__ ushort_t f2bf(float f) {
    unsigned u = __float_as_uint(f);
    u = (u + 0x7FFFu + ((u >> 16) & 1u)) >> 16;
    return (ushort_t)u;
}
__device__ __forceinline__ float bf2f(ushort_t u) {
    return __uint_as_float(((unsigned)u) << 16);
}

__device__ __forceinline__ float dot8(const float* s, bf16x8 w) {
    float a = 0.f;
#pragma unroll
    for (int b = 0; b < 8; ++b) a = fmaf(s[b], bf2f((ushort_t)w[b]), a);
    return a;
}
__device__ __forceinline__ float dot4(const float* s, bf16x4 w) {
    float a = 0.f;
#pragma unroll
    for (int b = 0; b < 4; ++b) a = fmaf(s[b], bf2f((ushort_t)w[b]), a);
    return a;
}

// ---- prep: scaled bf16 weight tables [col][16 k] + node_ftr zeroing (fused) ----
__global__ void prep_kernel(const float* __restrict__ fcW2,
                            const float* __restrict__ fc2W2,
                            ushort_t* __restrict__ W1t,
                            ushort_t* __restrict__ W2t,
                            float* __restrict__ node_ftr, int nfcount) {
    const float SQ3 = 1.7320508075688772f;
    const float cs1 = 0.14433756729740643f;   // 1/sqrt(48)
    const float cv1 = 0.20412414523193150f;   // 1/sqrt(24)
    const float cs2 = 0.25f;                  // 1/sqrt(16)
    const float cv2 = 0.35355339059327373f;   // 1/sqrt(8)
    int idx = blockIdx.x * blockDim.x + threadIdx.x;
    if (idx < 576 * 16) {
        int c = idx >> 4, k = idx & 15;
        float s = (c < 288) ? cs1 : (c < 432) ? cv1 : (c < 528) ? SQ3 * cs1 : cv1;
        W1t[idx] = f2bf(fcW2[k * 576 + c] * 0.25f * s);
    }
    if (idx < 144 * 16) {
        int c = idx >> 4, k = idx & 15;
        float s = (c < 64) ? cs2 : (c < 96) ? cv2 : (c < 128) ? SQ3 * cs2 : cv2;
        W2t[idx] = f2bf(fc2W2[k * 144 + c] * 0.25f * s);
    }
    if (idx < nfcount) node_ftr[idx] = 0.f;
}

// ---------------- edge kernel ----------------
__global__ __launch_bounds__(EPB) void edge_kernel(
    const float* __restrict__ hn, const float* __restrict__ he,
    const int* __restrict__ esrc, const int* __restrict__ edst,
    const float* __restrict__ evec, const float* __restrict__ emb,
    const float* __restrict__ enorm,
    const float* __restrict__ fcW1, const float* __restrict__ fc2W1,
    const ushort_t* __restrict__ W1t, const ushort_t* __restrict__ W2t,
    float* __restrict__ he_out, float* __restrict__ node_ftr, int E) {

    __shared__ ushort_t hh[EPB][HHS];   // per-edge h[16] | h2[16]
    __shared__ ushort_t W1L[ST][W1S];   // per-edge TP1 weights, i-major per o region
    __shared__ ushort_t W2L[ST][W2S];   // per-edge TP2 weights
    __shared__ ushort_t tmpL[ST][TPS];  // raw out0[12] | out1[4][3]

    const int tid  = threadIdx.x;
    const int wave = tid >> 6;
    const int lane = tid & 63;
    const int row  = lane & 15;
    const int g    = lane >> 4;
    const long long blk = blockIdx.x;

    // ---- B fragments once per block: 45 tiles (36 W1, 9 W2), 12 per wave ----
    bf16x8 Bf[12];
#pragma unroll
    for (int idx = 0; idx < 12; ++idx) {
        int t = wave + idx * 4;
        bf16x8 v = {};
        if (t < 45 && g < 2) {
            const ushort_t* src = (t < 36) ? (W1t + (t * 16 + row) * 16 + g * 8)
                                           : (W2t + ((t - 36) * 16 + row) * 16 + g * 8);
            v = *reinterpret_cast<const bf16x8*>(src);
        }
        Bf[idx] = v;
    }

    // ---- P0: per-edge MLP hidden layers -> LDS (bf16) ----
    {
        long long e0 = blk * EPB + tid;
        if (e0 < (long long)E) {
            float em[10];
#pragma unroll
            for (int i = 0; i < 10; ++i) em[i] = emb[e0 * 10 + i] * 0.31622776601683794f;
#pragma unroll
            for (int jj = 0; jj < 16; ++jj) {
                float a = 0.f, b = 0.f;
#pragma unroll
                for (int i = 0; i < 10; ++i) {
                    a = fmaf(em[i], fcW1[i * 16 + jj], a);
                    b = fmaf(em[i], fc2W1[i * 16 + jj], b);
                }
                hh[tid][jj]      = f2bf(frelu(a));
                hh[tid][16 + jj] = f2bf(frelu(b));
            }
        } else {
#pragma unroll
            for (int jj = 0; jj < 32; ++jj) hh[tid][jj] = 0;
        }
    }
    __syncthreads();

    const int le = tid & 15;   // edge within subtile
    const int j  = tid >> 4;   // 16 consumer threads per edge (j uniform per 16-lane group)

    for (int st = 0; st < 16; ++st) {
        long long ge = blk * EPB + st * ST + le;
        bool on = ge < (long long)E;

        // ---- prefetch consume data (hides under GEMM) ----
        int nd = 0;
        float ex = 0, ey = 0, ez = 0, nw = 0;
        float her[20], hsr[20], hdr[20];
        if (on) {
            int ns = esrc[ge];
            nd = edst[ge];
            ex = evec[ge * 3 + 0]; ey = evec[ge * 3 + 1]; ez = evec[ge * 3 + 2];
            nw = enorm[ge];
            const float* hp = he + ge * 20;
            const float* sp = hn + (long long)ns * 20;
            const float* dp = hn + (long long)nd * 20;
#pragma unroll
            for (int q = 0; q < 20; ++q) { her[q] = hp[q]; hsr[q] = sp[q]; hdr[q] = dp[q]; }
        } else {
#pragma unroll
            for (int q = 0; q < 20; ++q) { her[q] = 0; hsr[q] = 0; hdr[q] = 0; }
        }

        // ---- GEMM: materialize W1eff/W2eff for this 16-edge subtile ----
        bf16x8 A1 = {}, A2 = {};
        if (g < 2) {
            A1 = *reinterpret_cast<const bf16x8*>(&hh[st * ST + row][g * 8]);
            A2 = *reinterpret_cast<const bf16x8*>(&hh[st * ST + row][16 + g * 8]);
        }
#pragma unroll
        for (int idx = 0; idx < 12; ++idx) {
            int t = wave + idx * 4;
            if (t >= 45) continue;                 // wave-uniform skip
            bool isg1 = (t < 36);
            int c = (isg1 ? t * 16 : (t - 36) * 16) + row;
            int off;
            if (isg1) {
                if (c < 288)      { int i = c / 12,          o = c % 12;         off = o * 24 + i; }
                else if (c < 432) { int i = (c - 288) / 12,  o = (c - 288) % 12; off = 288 + o * 12 + i; }
                else if (c < 528) { int i = (c - 432) >> 2,  o = (c - 432) & 3;  off = 432 + o * 24 + i; }
                else              { int i = (c - 528) >> 2,  o = (c - 528) & 3;  off = 528 + o * 12 + i; }
            } else {
                if (c < 64)       { int i = c >> 3,          o = c & 7;          off = o * 8 + i; }
                else if (c < 96)  { int i = (c - 64) >> 3,   o = (c - 64) & 7;   off = 64 + o * 4 + i; }
                else if (c < 128) { int i = (c - 96) >> 2,   o = (c - 96) & 3;   off = 96 + o * 8 + i; }
                else              { int i = (c - 128) >> 2,  o = (c - 128) & 3;  off = 128 + o * 4 + i; }
            }
            f32x4 zero = {0.f, 0.f, 0.f, 0.f};
            f32x4 d = __builtin_amdgcn_mfma_f32_16x16x32_bf16(isg1 ? A1 : A2, Bf[idx], zero, 0, 0, 0);
            int r0 = g * 4;                        // edge row within subtile
            if (isg1) {
#pragma unroll
                for (int r = 0; r < 4; ++r) W1L[r0 + r][off] = f2bf(d[r]);
            } else {
#pragma unroll
                for (int r = 0; r < 4; ++r) W2L[r0 + r][off] = f2bf(d[r]);
            }
        }
        __syncthreads();

        // ---- consume 1: TP1 + gate prep (16 threads/edge, one column each) ----
        float u0 = 0, u1 = 0, u2 = 0;
        if (on) {
            float inv = 1.0f / (sqrtf(fmaf(ex, ex, fmaf(ey, ey, ez * ez))) + 1e-12f);
            u0 = ex * inv; u1 = ey * inv; u2 = ez * inv;
            const ushort_t* base = &W1L[le][0];

            if (j < 12) {           // waves 0-2: out0 col o = j
                float dots[12];
#pragma unroll
                for (int i = 0; i < 4; ++i) {
                    dots[i]     = fmaf(her[8 + i * 3], u0, fmaf(her[9 + i * 3], u1, her[10 + i * 3] * u2));
                    dots[4 + i] = fmaf(hsr[8 + i * 3], u0, fmaf(hsr[9 + i * 3], u1, hsr[10 + i * 3] * u2));
                    dots[8 + i] = fmaf(hdr[8 + i * 3], u0, fmaf(hdr[9 + i * 3], u1, hdr[10 + i * 3] * u2));
                }
                int o = j;
                bf16x8 wa = *reinterpret_cast<const bf16x8*>(base + o * 24);
                bf16x8 wb = *reinterpret_cast<const bf16x8*>(base + o * 24 + 8);
                bf16x8 wc = *reinterpret_cast<const bf16x8*>(base + o * 24 + 16);
                float acc = dot8(her, wa) + dot8(hsr, wb) + dot8(hdr, wc);
                bf16x4 va = *reinterpret_cast<const bf16x4*>(base + 288 + o * 12);
                bf16x4 vb = *reinterpret_cast<const bf16x4*>(base + 288 + o * 12 + 4);
                bf16x4 vc = *reinterpret_cast<const bf16x4*>(base + 288 + o * 12 + 8);
                acc += dot4(dots, va) + dot4(dots + 4, vb) + dot4(dots + 8, vc);
                tmpL[le][o] = f2bf(acc);
            } else {                // wave 3: out1 o = j-12 (raw, pre-gate)
                int o = j - 12;
                bf16x8 p0 = *reinterpret_cast<const bf16x8*>(base + 432 + o * 24);
                bf16x8 p1 = *reinterpret_cast<const bf16x8*>(base + 432 + o * 24 + 8);
                bf16x8 p2 = *reinterpret_cast<const bf16x8*>(base + 432 + o * 24 + 16);
                float q = dot8(her, p0) + dot8(hsr, p1) + dot8(hdr, p2);
                bf16x4 q0 = *reinterpret_cast<const bf16x4*>(base + 528 + o * 12);
                bf16x4 q1 = *reinterpret_cast<const bf16x4*>(base + 528 + o * 12 + 4);
                bf16x4 q2 = *reinterpret_cast<const bf16x4*>(base + 528 + o * 12 + 8);
                float vx = 0, vy = 0, vz = 0;
#pragma unroll
                for (int i = 0; i < 4; ++i) {
                    float w = bf2f((ushort_t)q0[i]);
                    vx = fmaf(her[8 + i * 3], w, vx); vy = fmaf(her[9 + i * 3], w, vy); vz = fmaf(her[10 + i * 3], w, vz);
                }
#pragma unroll
                for (int i = 0; i < 4; ++i) {
                    float w = bf2f((ushort_t)q1[i]);
                    vx = fmaf(hsr[8 + i * 3], w, vx); vy = fmaf(hsr[9 + i * 3], w, vy); vz = fmaf(hsr[10 + i * 3], w, vz);
                }
#pragma unroll
                for (int i = 0; i < 4; ++i) {
                    float w = bf2f((ushort_t)q2[i]);
                    vx = fmaf(hdr[8 + i * 3], w, vx); vy = fmaf(hdr[9 + i * 3], w, vy); vz = fmaf(hdr[10 + i * 3], w, vz);
                }
                tmpL[le][12 + 3 * o + 0] = f2bf(fmaf(q, u0, vx));
                tmpL[le][12 + 3 * o + 1] = f2bf(fmaf(q, u1, vy));
                tmpL[le][12 + 3 * o + 2] = f2bf(fmaf(q, u2, vz));
            }
        }
        __syncthreads();

        // ---- consume 2: gate + TP2 + outputs + scatter ----
        if (on && j < 12) {
            bf16x8 t0 = *reinterpret_cast<const bf16x8*>(&tmpL[le][0]);
            bf16x8 t1 = *reinterpret_cast<const bf16x8*>(&tmpL[le][8]);
            bf16x8 t2 = *reinterpret_cast<const bf16x8*>(&tmpL[le][16]);
            float ts[8];
#pragma unroll
            for (int b = 0; b < 8; ++b) ts[b] = frelu(bf2f((ushort_t)t0[b]));
            float gt[4];
#pragma unroll
            for (int o = 0; o < 4; ++o) gt[o] = frelu(bf2f((ushort_t)t1[o]));
            float tv[4][3];
#pragma unroll
            for (int o = 0; o < 4; ++o) {
#pragma unroll
                for (int c = 0; c < 3; ++c) {
                    int sl = 12 + 3 * o + c;
                    float raw = (sl < 16) ? bf2f((ushort_t)t1[sl - 8]) : bf2f((ushort_t)t2[sl - 16]);
                    tv[o][c] = raw * gt[o];
                }
            }
            float d2[4];
#pragma unroll
            for (int i = 0; i < 4; ++i) d2[i] = fmaf(tv[i][0], u0, fmaf(tv[i][1], u1, tv[i][2] * u2));

            const ushort_t* b2 = &W2L[le][0];
            float* hep = he_out + ge * 20;
            float* nf  = node_ftr + (long long)nd * 20;

            if (j < 8) {
                // scalar output col o = j
                bf16x8 wss = *reinterpret_cast<const bf16x8*>(b2 + j * 8);
                bf16x4 wvs = *reinterpret_cast<const bf16x4*>(b2 + 64 + j * 4);
                float dval = dot8(ts, wss) + dot4(d2, wvs);
                float oS = he[ge * 20 + j] + dval;     // L1-hot reload (avoids runtime reg-index)
                hep[j] = oS;
                atomicAdd(nf + j, oS * nw);
            } else {
                // vector output o = j-8
                int o = j - 8;
                bf16x8 wsv = *reinterpret_cast<const bf16x8*>(b2 + 96 + o * 8);
                float q2s = dot8(ts, wsv);
                bf16x4 wvv = *reinterpret_cast<const bf16x4*>(b2 + 128 + o * 4);
                float e0c = 0, e1c = 0, e2c = 0;
#pragma unroll
                for (int i = 0; i < 4; ++i) {
                    float w = bf2f((ushort_t)wvv[i]);
                    e0c = fmaf(tv[i][0], w, e0c); e1c = fmaf(tv[i][1], w, e1c); e2c = fmaf(tv[i][2], w, e2c);
                }
                float d1c[3] = { fmaf(q2s, u0, e0c), fmaf(q2s, u1, e1c), fmaf(q2s, u2, e2c) };
#pragma unroll
                for (int c = 0; c < 3; ++c) {
                    float oV = he[ge * 20 + 8 + 3 * o + c] + d1c[c];
                    hep[8 + 3 * o + c] = oV;
                    atomicAdd(nf + 8 + 3 * o + c, oV * nw);
                }
            }
        }
        __syncthreads();
    }
}

// ---------------- node kernel (unchanged, verified) ----------------
__global__ __launch_bounds__(256) void node_kernel(
    const float* __restrict__ hn, const float* __restrict__ node_ftr,
    const float* __restrict__ WgS, const float* __restrict__ WgV,
    const float* __restrict__ WoS, const float* __restrict__ WoV,
    float* __restrict__ out, int N) {
    int n = blockIdx.x * blockDim.x + threadIdx.x;
    if (n >= N) return;
    const float* hr = hn + (size_t)n * 20;
    const float* fr = node_ftr + (size_t)n * 20;
    const float rs16 = 0.25f, rs8 = 0.35355339059327373f, rs4 = 0.5f;

    float cs[16], cvx[8], cvy[8], cvz[8];
#pragma unroll
    for (int i = 0; i < 8; ++i) { cs[i] = hr[i]; cs[8 + i] = fr[i]; }
#pragma unroll
    for (int i = 0; i < 4; ++i) {
        cvx[i] = hr[8 + i * 3]; cvy[i] = hr[8 + i * 3 + 1]; cvz[i] = hr[8 + i * 3 + 2];
        cvx[4 + i] = fr[8 + i * 3]; cvy[4 + i] = fr[8 + i * 3 + 1]; cvz[4 + i] = fr[8 + i * 3 + 2];
    }
    float gl[12];
#pragma unroll
    for (int o = 0; o < 12; ++o) {
        float a = 0.f;
#pragma unroll
        for (int i = 0; i < 16; ++i) a = fmaf(cs[i], WgS[i * 12 + o], a);
        gl[o] = a * rs16;
    }
    float vlx[4], vly[4], vlz[4];
#pragma unroll
    for (int o = 0; o < 4; ++o) {
        float ax = 0.f, ay = 0.f, az = 0.f;
#pragma unroll
        for (int i = 0; i < 8; ++i) {
            float w = WgV[i * 4 + o];
            ax = fmaf(cvx[i], w, ax); ay = fmaf(cvy[i], w, ay); az = fmaf(cvz[i], w, az);
        }
        float gv = frelu(gl[8 + o]);
        vlx[o] = ax * rs8 * gv; vly[o] = ay * rs8 * gv; vlz[o] = az * rs8 * gv;
    }
    float ls[8];
#pragma unroll
    for (int i = 0; i < 8; ++i) ls[i] = frelu(gl[i]);
    float* op = out + (size_t)n * 20;
#pragma unroll
    for (int o = 0; o < 8; ++o) {
        float a = 0.f;
#pragma unroll
        for (int i = 0; i < 8; ++i) a = fmaf(ls[i], WoS[i * 8 + o], a);
        op[o] = hr[o] + a * rs8;
    }
#pragma unroll
    for (int o = 0; o < 4; ++o) {
        float ax = 0.f, ay = 0.f, az = 0.f;
#pragma unroll
        for (int i = 0; i < 4; ++i) {
            float w = WoV[i * 4 + o];
            ax = fmaf(vlx[i], w, ax); ay = fmaf(vly[i], w, ay); az = fmaf(vlz[i], w, az);
        }
        op[8 + o * 3 + 0] = hr[8 + o * 3 + 0] + ax * rs4;
        op[8 + o * 3 + 1] = hr[8 + o * 3 + 1] + ay * rs4;
        op[8 + o * 3 + 2] = hr[8 + o * 3 + 2] + az * rs4;
    }
}

extern "C" void kernel_launch(void* const* d_in, const int* in_sizes, int n_in,
                              void* d_out, int out_size, void* d_ws, size_t ws_size,
                              hipStream_t stream) {
    const float* hn    = (const float*)d_in[0];
    const float* he    = (const float*)d_in[1];
    const int*   esrc  = (const int*)d_in[2];
    const int*   edst  = (const int*)d_in[3];
    const float* evec  = (const float*)d_in[4];
    const float* emb   = (const float*)d_in[5];
    const float* enorm = (const float*)d_in[6];
    const float* fcW1  = (const float*)d_in[8];
    const float* fcW2  = (const float*)d_in[9];
    const float* fc2W1 = (const float*)d_in[10];
    const float* fc2W2 = (const float*)d_in[11];
    const float* WgS   = (const float*)d_in[12];
    const float* WgV   = (const float*)d_in[13];
    const float* WoS   = (const float*)d_in[14];
    const float* WoV   = (const float*)d_in[15];

    int N = in_sizes[0] / 20;
    int E = in_sizes[1] / 20;

    float* out      = (float*)d_out;
    float* he_out   = out + (size_t)N * 20;
    float* node_ftr = (float*)d_ws;                           // N*20 f32
    ushort_t* W1t   = (ushort_t*)(node_ftr + (size_t)N * 20); // 576*16 bf16
    ushort_t* W2t   = W1t + 576 * 16;                         // 144*16 bf16

    int nfcount = N * 20;
    int prep_work = (nfcount > 576 * 16) ? nfcount : 576 * 16;
    prep_kernel<<<(prep_work + 255) / 256, 256, 0, stream>>>(fcW2, fc2W2, W1t, W2t, node_ftr, nfcount);
    edge_kernel<<<(E + EPB - 1) / EPB, EPB, 0, stream>>>(
        hn, he, esrc, edst, evec, emb, enorm, fcW1, fc2W1, W1t, W2t, he_out, node_ftr, E);
    node_kernel<<<(N + 255) / 256, 256, 0, stream>>>(hn, node_ftr, WgS, WgV, WoS, WoV, out, N);
}